// Round 1
// 600.992 us; speedup vs baseline: 1.1865x; 1.1865x over previous
//
#include <hip/hip_runtime.h>
#include <hip/hip_bf16.h>
#include <cstdint>
#include <cstddef>

typedef __hip_bfloat16 bf16;
typedef __attribute__((ext_vector_type(8))) short bf16x8;
typedef __attribute__((ext_vector_type(4))) float f32x4;

#define NN 50000
#define NE 400000

struct PTab {
    const void* p[17];
    int n[17];
};

__device__ __forceinline__ float bf2f(unsigned short u) {
    return __uint_as_float(((unsigned)u) << 16);
}
__device__ __forceinline__ unsigned short f2bf(float f) {
    __hip_bfloat16 h = __float2bfloat16(f);
    return *reinterpret_cast<unsigned short*>(&h);
}
__device__ __forceinline__ float fin(float v) {
    return (v == v && v > -1e30f && v < 1e30f) ? v : 0.0f;
}
__device__ __forceinline__ float rd(const void* p, int i, int f) {
    return f ? ((const float*)p)[i] : bf2f(((const unsigned short*)p)[i]);
}

// async global -> LDS, 16B per lane, dest = wave-uniform base + lane*16
__device__ __forceinline__ void gl16(const void* g, void* l) {
    __builtin_amdgcn_global_load_lds(
        (const __attribute__((address_space(1))) unsigned int*)g,
        (__attribute__((address_space(3))) unsigned int*)l, 16, 0, 0);
}

// ---- probe dtypes: flags[t]=1 fp32 / 0 bf16 (t=0..16); flags[17]=1 int32 ei ----
__global__ void k_probe(PTab tab, const int* __restrict__ ei, int* __restrict__ flags) {
    __shared__ int zc, bc, sAny;
    for (int t = 0; t < 17; ++t) {
        if (threadIdx.x == 0) { zc = 0; bc = 0; }
        __syncthreads();
        int words = tab.n[t] >> 1;
        if (words > 256) words = 256;
        if ((int)threadIdx.x < words) {
            unsigned w = ((const unsigned*)tab.p[t])[threadIdx.x];
            if (w == 0u) atomicAdd(&zc, 1);
            else {
                int e = (w >> 7) & 0xFF;
                if (e >= 100 && e <= 140) atomicAdd(&bc, 1);
            }
        }
        __syncthreads();
        if (threadIdx.x == 0) {
            int nz = words - zc;
            flags[t] = (nz == 0 || 2 * bc >= nz) ? 0 : 1;
        }
        __syncthreads();
    }
    if (threadIdx.x == 0) sAny = 0;
    __syncthreads();
    int any = 0;
    for (int i = threadIdx.x; i < 2048; i += 256) any |= ei[2 * i + 1];
    if (any) sAny = 1;
    __syncthreads();
    if (threadIdx.x == 0) flags[17] = sAny;
}

// ---- split W into transposed bf16 hi/lo: [rows][Kp], zero-padded ----
__global__ void k_wsplit(const void* __restrict__ W, const int* __restrict__ flags, int fidx,
                         int K, int M, int Kp,
                         unsigned short* __restrict__ wh, unsigned short* __restrict__ wl) {
    int n = blockIdx.x;
    int k = threadIdx.x;
    if (k >= Kp) return;
    float v = 0.0f;
    if (k < K && n < M) v = fin(rd(W, k * M + n, flags[fidx]));
    unsigned short hi = f2bf(v);
    unsigned short lo = f2bf(v - bf2f(hi));
    wh[(size_t)n * Kp + k] = hi;
    wl[(size_t)n * Kp + k] = lo;
}

struct MOff { int m[8]; int mp[8]; };

// ---- all 8 biases, zero-padded to mp[l] ----
__global__ void k_biasall(PTab tab, const int* __restrict__ flags, MOff mo,
                          float* __restrict__ dst) {
    int l = blockIdx.x;
    int fidx = 2 + 2 * l;
    int M = tab.n[fidx];
    int i = threadIdx.x;
    if (i < mo.mp[l])
        dst[mo.m[l] + i] = (i < M) ? fin(rd(tab.p[fidx], i, flags[fidx])) : 0.0f;
}

__global__ void k_repack(const int* __restrict__ ei, const int* __restrict__ flags,
                         int* __restrict__ src, int* __restrict__ dst) {
    int e = blockIdx.x * blockDim.x + threadIdx.x;
    if (e >= NE) return;
    int s, d;
    if (flags[17]) { s = ei[e]; d = ei[NE + e]; }
    else           { s = ei[2 * e]; d = ei[2 * (NE + e)]; }
    src[e] = min(max(s, 0), NN - 1);
    dst[e] = min(max(d, 0), NN - 1);
}

__global__ void k_zero2(int* __restrict__ a, int* __restrict__ b, int n) {
    int i = blockIdx.x * blockDim.x + threadIdx.x;
    if (i < n) { a[i] = 0; b[i] = 0; }
}

__global__ void k_count(const int* __restrict__ dst, int* __restrict__ deg) {
    int e = blockIdx.x * blockDim.x + threadIdx.x;
    if (e < NE) atomicAdd(&deg[dst[e]], 1);
}

__global__ void k_scan1(const int* __restrict__ deg, int* __restrict__ rowp,
                        int* __restrict__ part) {
    __shared__ int s[512];
    int tid = threadIdx.x, i = blockIdx.x * 512 + tid;
    int v = (i < NN) ? deg[i] : 0;
    s[tid] = v;
    __syncthreads();
    for (int off = 1; off < 512; off <<= 1) {
        int t = (tid >= off) ? s[tid - off] : 0;
        __syncthreads();
        s[tid] += t;
        __syncthreads();
    }
    if (i < NN) rowp[i] = s[tid] - v;
    if (tid == 511) part[blockIdx.x] = s[511];
}
__global__ void k_scan2(int* __restrict__ part, int nb) {
    __shared__ int s[128];
    int tid = threadIdx.x;
    int v = (tid < nb) ? part[tid] : 0;
    s[tid] = v;
    __syncthreads();
    for (int off = 1; off < 128; off <<= 1) {
        int t = (tid >= off) ? s[tid - off] : 0;
        __syncthreads();
        s[tid] += t;
        __syncthreads();
    }
    if (tid < nb) part[tid] = s[tid] - v;
}
__global__ void k_scan3(int* __restrict__ rowp, const int* __restrict__ part,
                        const int* __restrict__ deg, float* __restrict__ dinv) {
    int i = blockIdx.x * blockDim.x + threadIdx.x;
    if (i < NN) {
        rowp[i] += part[i >> 9];
        dinv[i] = rsqrtf((float)deg[i] + 1.0f);
    }
    if (i == 0) rowp[NN] = NE;
}

__global__ void k_fill(const int* __restrict__ src, const int* __restrict__ dst,
                       const int* __restrict__ rowp, int* __restrict__ cursor,
                       int* __restrict__ colv) {
    int e = blockIdx.x * blockDim.x + threadIdx.x;
    if (e >= NE) return;
    int d = dst[e];
    int p = atomicAdd(&cursor[d], 1);
    colv[rowp[d] + p] = src[e];
}

// ---- xs = bf16(x * dinv), stride 128 ----
__global__ void k_xin(const void* __restrict__ x, const int* __restrict__ flags,
                      const float* __restrict__ dinv, unsigned short* __restrict__ xs) {
    int t = blockIdx.x * blockDim.x + threadIdx.x;
    if (t >= NN * 16) return;
    int i = t >> 4, c = (t & 15) * 8;
    float d = dinv[i];
    int f = flags[0];
    const float* xf = (const float*)x + (size_t)i * 128 + c;
    const unsigned short* xb = (const unsigned short*)x + (size_t)i * 128 + c;
    unsigned short o[8];
    #pragma unroll
    for (int j = 0; j < 8; ++j)
        o[j] = f2bf(fin(f ? xf[j] : bf2f(xb[j])) * d);
    *(uint4*)(xs + (size_t)i * 128 + c) = *(uint4*)o;
}

// ---- CSR gather, fused-width: out[i]=dinv[i]*(in[i]+sum in[colv[j]]) ----
// lanes<=16: 4 edge-slots of 16 lanes + shuffle reduce (all 64 lanes busy)
// lanes>16 : single slot, 4-edge unroll for MLP
__launch_bounds__(256)
__global__ void k_gather(const unsigned short* __restrict__ in, int istride,
                         unsigned short* __restrict__ out, int ostride, int lanes,
                         const int* __restrict__ rowp, const int* __restrict__ colv,
                         const float* __restrict__ dinv) {
    const int node = blockIdx.x * 4 + (threadIdx.x >> 6);
    if (node >= NN) return;
    const int lane = threadIdx.x & 63;
    const int beg = rowp[node], end = rowp[node + 1];
    float a[8] = {0.f, 0.f, 0.f, 0.f, 0.f, 0.f, 0.f, 0.f};
    if (lanes <= 16) {
        const int slot = lane >> 4;
        const int l8 = lane & 15;
        const bool on = l8 < lanes;
        const size_t off = (size_t)l8 * 8;
        if (slot == 0 && on) {          // self term once, in slot 0
            uint4 q = *(const uint4*)(in + (size_t)node * istride + off);
            unsigned v[4] = {q.x, q.y, q.z, q.w};
            #pragma unroll
            for (int t = 0; t < 4; ++t) {
                a[2 * t] += bf2f(v[t] & 0xFFFF); a[2 * t + 1] += bf2f(v[t] >> 16);
            }
        }
        for (int j = beg + slot; j < end; j += 4) {
            const int s = colv[j];
            if (on) {
                uint4 q = *(const uint4*)(in + (size_t)s * istride + off);
                unsigned v[4] = {q.x, q.y, q.z, q.w};
                #pragma unroll
                for (int t = 0; t < 4; ++t) {
                    a[2 * t] += bf2f(v[t] & 0xFFFF); a[2 * t + 1] += bf2f(v[t] >> 16);
                }
            }
        }
        #pragma unroll
        for (int t = 0; t < 8; ++t) {
            a[t] += __shfl_xor(a[t], 16);
            a[t] += __shfl_xor(a[t], 32);
        }
        if (lane < lanes) {
            float d = dinv[node];
            unsigned short o[8];
            #pragma unroll
            for (int t = 0; t < 8; ++t) o[t] = f2bf(a[t] * d);
            *(uint4*)(out + (size_t)node * ostride + (size_t)lane * 8) = *(uint4*)o;
        }
    } else {
        const bool on = lane < lanes;
        const size_t off = (size_t)lane * 8;
        if (on) {
            uint4 q = *(const uint4*)(in + (size_t)node * istride + off);
            unsigned v[4] = {q.x, q.y, q.z, q.w};
            #pragma unroll
            for (int t = 0; t < 4; ++t) {
                a[2 * t] += bf2f(v[t] & 0xFFFF); a[2 * t + 1] += bf2f(v[t] >> 16);
            }
        }
        int j = beg;
        for (; j + 3 < end; j += 4) {
            int s0 = colv[j], s1 = colv[j + 1], s2 = colv[j + 2], s3 = colv[j + 3];
            if (on) {
                uint4 q0 = *(const uint4*)(in + (size_t)s0 * istride + off);
                uint4 q1 = *(const uint4*)(in + (size_t)s1 * istride + off);
                uint4 q2 = *(const uint4*)(in + (size_t)s2 * istride + off);
                uint4 q3 = *(const uint4*)(in + (size_t)s3 * istride + off);
                unsigned v0[4] = {q0.x, q0.y, q0.z, q0.w};
                unsigned v1[4] = {q1.x, q1.y, q1.z, q1.w};
                unsigned v2[4] = {q2.x, q2.y, q2.z, q2.w};
                unsigned v3[4] = {q3.x, q3.y, q3.z, q3.w};
                #pragma unroll
                for (int t = 0; t < 4; ++t) {
                    a[2 * t]     += bf2f(v0[t] & 0xFFFF) + bf2f(v1[t] & 0xFFFF)
                                  + bf2f(v2[t] & 0xFFFF) + bf2f(v3[t] & 0xFFFF);
                    a[2 * t + 1] += bf2f(v0[t] >> 16) + bf2f(v1[t] >> 16)
                                  + bf2f(v2[t] >> 16) + bf2f(v3[t] >> 16);
                }
            }
        }
        for (; j < end; ++j) {
            int s = colv[j];
            if (on) {
                uint4 q = *(const uint4*)(in + (size_t)s * istride + off);
                unsigned v[4] = {q.x, q.y, q.z, q.w};
                #pragma unroll
                for (int t = 0; t < 4; ++t) {
                    a[2 * t] += bf2f(v[t] & 0xFFFF); a[2 * t + 1] += bf2f(v[t] >> 16);
                }
            }
        }
        if (on) {
            float d = dinv[node];
            unsigned short o[8];
            #pragma unroll
            for (int t = 0; t < 8; ++t) o[t] = f2bf(a[t] * d);
            *(uint4*)(out + (size_t)node * ostride + off) = *(uint4*)o;
        }
    }
}

// ---- MFMA GEMM: global_load_lds staging, linear+XOR-swizzled LDS, 1-ahead
//      double buffer, 1 barrier per K-step. 2-term split (A bf16, W hi/lo). ----
__launch_bounds__(256, 3)
__global__ void k_mgemm(const unsigned short* __restrict__ A, int astride,
                        const unsigned short* __restrict__ Wh,
                        const unsigned short* __restrict__ Wl, int Kp,
                        const float* __restrict__ bias, const float* __restrict__ dinv,
                        void* __restrict__ out, int ostride, int M, int OutW, int act) {
    __shared__ unsigned short sA[2][128][32];
    __shared__ unsigned short sBh[2][128][32];
    __shared__ unsigned short sBl[2][128][32];
    const int tid = threadIdx.x;
    const int wave = tid >> 6, lane = tid & 63;
    const int wr = wave >> 1, wc = wave & 1;
    const int quad = lane >> 4, m16 = lane & 15;
    const int row0 = blockIdx.x * 128, col0 = blockIdx.y * 128;

    // staging: wave stages rows [wave*32, wave*32+32); lane -> (row, 16B unit)
    const int lr = lane >> 2;                                   // row within 16-row chunk
    const int swz = ((lane >> 2) ^ (lane >> 4)) & 3;            // s(row) for dest row
    const int su = ((lane & 3) ^ swz) * 8;                      // pre-swizzled src elem off

    int ar1 = row0 + wave * 32 + lr;      if (ar1 >= NN) ar1 = NN - 1;
    int ar2 = row0 + wave * 32 + 16 + lr; if (ar2 >= NN) ar2 = NN - 1;
    const unsigned short* gA1 = A + (size_t)ar1 * astride + su;
    const unsigned short* gA2 = A + (size_t)ar2 * astride + su;
    const int br = col0 + wave * 32 + lr;
    const unsigned short* gBh1 = Wh + (size_t)br * Kp + su;
    const unsigned short* gBl1 = Wl + (size_t)br * Kp + su;

    f32x4 zz = {0.f, 0.f, 0.f, 0.f};
    f32x4 acc[4][4];
    #pragma unroll
    for (int i = 0; i < 4; ++i)
        #pragma unroll
        for (int j = 0; j < 4; ++j) acc[i][j] = zz;

    // read-side swizzle: unit = quad ^ s(row); lane-constant
    const int rs = (quad ^ ((m16 & 3) ^ ((m16 >> 2) & 3))) * 8;
    const int nk = Kp >> 5;

    auto stage = [&](int b, int k0) {
        gl16(gA1 + k0,               &sA[b][wave * 32][0]);
        gl16(gA2 + k0,               &sA[b][wave * 32 + 16][0]);
        gl16(gBh1 + k0,              &sBh[b][wave * 32][0]);
        gl16(gBh1 + 16 * Kp + k0,    &sBh[b][wave * 32 + 16][0]);
        gl16(gBl1 + k0,              &sBl[b][wave * 32][0]);
        gl16(gBl1 + 16 * Kp + k0,    &sBl[b][wave * 32 + 16][0]);
    };

    stage(0, 0);
    __syncthreads();
    int cur = 0;
    for (int ks = 0; ks < nk; ++ks) {
        if (ks + 1 < nk) stage(cur ^ 1, (ks + 1) * 32);   // issue next tile before compute
        bf16x8 fa[4], fh[4], fl[4];
        #pragma unroll
        for (int i = 0; i < 4; ++i) {
            fa[i] = *(const bf16x8*)&sA[cur][wr * 64 + i * 16 + m16][rs];
            fh[i] = *(const bf16x8*)&sBh[cur][wc * 64 + i * 16 + m16][rs];
            fl[i] = *(const bf16x8*)&sBl[cur][wc * 64 + i * 16 + m16][rs];
        }
        #pragma unroll
        for (int i = 0; i < 4; ++i)
            #pragma unroll
            for (int j = 0; j < 4; ++j) {
                acc[i][j] = __builtin_amdgcn_mfma_f32_16x16x32_bf16(fa[i], fh[j], acc[i][j], 0, 0, 0);
                acc[i][j] = __builtin_amdgcn_mfma_f32_16x16x32_bf16(fa[i], fl[j], acc[i][j], 0, 0, 0);
            }
        __syncthreads();   // drains vmcnt: next buffer ready; reads of cur done
        cur ^= 1;
    }

    #pragma unroll
    for (int j = 0; j < 4; ++j) {
        int col = col0 + wc * 64 + j * 16 + m16;
        if (col >= OutW) continue;
        float bcol = (col < M) ? bias[col] : 0.0f;
        #pragma unroll
        for (int i = 0; i < 4; ++i) {
            #pragma unroll
            for (int r = 0; r < 4; ++r) {
                int row = row0 + wr * 64 + i * 16 + quad * 4 + r;
                if (row >= NN) continue;
                if (act) {
                    float v = (col < M) ? 1.0f / (1.0f + expf(-(acc[i][j][r] + bcol))) : 0.0f;
                    ((float*)out)[(size_t)row * ostride + col] = v;
                } else {
                    float v = (col < M) ? fmaxf(acc[i][j][r] + bcol, 0.0f) * dinv[row] : 0.0f;
                    ((unsigned short*)out)[(size_t)row * ostride + col] = f2bf(v);
                }
            }
        }
    }
}

__global__ void k_sentinel(float* __restrict__ out, int n) {
    int i = blockIdx.x * blockDim.x + threadIdx.x;
    if (i < n) out[i] = 4.0f;
}

extern "C" void kernel_launch(void* const* d_in, const int* in_sizes, int n_in,
                              void* d_out, int out_size, void* d_ws, size_t ws_size,
                              hipStream_t stream) {
    const int* ei = (const int*)d_in[1];
    float* out_e = (float*)d_out;
    float* out_v = out_e + (size_t)NN * 256;

    const int wsz[16] = {128 * 166, 166, 166 * 192, 192, 192 * 218, 218, 218 * 256, 256,
                         128 * 128, 128, 128 * 128, 128, 128 * 128, 128, 128 * 128, 128};
    PTab tab;
    tab.p[0] = d_in[0]; tab.n[0] = NN * 128;
    for (int t = 0; t < 16; ++t) { tab.p[t + 1] = d_in[2 + t]; tab.n[t + 1] = wsz[t]; }

    // weight storage: l=0 is merged [W1e(pad192) | W1n] 384x128; l=4 unused
    const int KpW[8] = {128, 192, 192, 224, 0, 128, 128, 128};
    const int MpW[8] = {384, 256, 256, 256, 0, 128, 128, 128};

    char* wsb = (char*)d_ws;
    size_t o = 0;
    auto align = [](size_t v) { return (v + 255) & ~(size_t)255; };
    int*   flags  = (int*)(wsb + o);  o = align(o + 128);
    int*   colv   = (int*)(wsb + o);  o = align(o + (size_t)NE * 4);
    int*   deg    = (int*)(wsb + o);  o = align(o + (size_t)NN * 4);
    int*   cursor = (int*)(wsb + o);  o = align(o + (size_t)NN * 4);
    int*   rowp   = (int*)(wsb + o);  o = align(o + (size_t)(NN + 1) * 4);
    int*   part   = (int*)(wsb + o);  o = align(o + 512);
    float* dinv   = (float*)(wsb + o); o = align(o + (size_t)NN * 4);
    unsigned short* wh[8]; unsigned short* wl[8];
    for (int l = 0; l < 8; ++l) {
        size_t wel = (size_t)MpW[l] * KpW[l];
        wh[l] = (unsigned short*)(wsb + o); o = align(o + wel * 2);
        wl[l] = (unsigned short*)(wsb + o); o = align(o + wel * 2);
    }
    float* ball = (float*)(wsb + o); o = align(o + 1376 * 4);
    unsigned short* bufA = (unsigned short*)(wsb + o); o = align(o + (size_t)NN * 352 * 2);
    unsigned short* bufB = (unsigned short*)(wsb + o); o = align(o + (size_t)NN * 352 * 2);
    // src32/dst32 alias bufB head: dead after k_fill, bufB first written by gather0
    int* src32 = (int*)bufB;
    int* dst32 = src32 + NE;
    if (o > ws_size) {
        k_sentinel<<<(out_size + 255) / 256, 256, 0, stream>>>(out_e, out_size);
        return;
    }

    // bias packing: merged L1 bias = [b1e pad192 | b1n] at [0,320)
    MOff mo;
    const int moff[8] = {0, 320, 512, 736, 192, 992, 1120, 1248};
    const int mpad[8] = {192, 192, 224, 256, 128, 128, 128, 128};
    for (int l = 0; l < 8; ++l) { mo.m[l] = moff[l]; mo.mp[l] = mpad[l]; }

    const int EB = (NE + 255) / 256;
    const int NB512 = (NN + 511) / 512;
    const int GX = (NN + 127) / 128;
    const int GN = (NN + 3) / 4;

    k_probe<<<1, 256, 0, stream>>>(tab, ei, flags);
    k_wsplit<<<192, 256, 0, stream>>>(d_in[2],  flags, 1,  128, 166, 128, wh[0], wl[0]);
    k_wsplit<<<192, 256, 0, stream>>>(d_in[10], flags, 9,  128, 128, 128,
                                      wh[0] + 192 * 128, wl[0] + 192 * 128);
    k_wsplit<<<256, 256, 0, stream>>>(d_in[4],  flags, 3,  166, 192, 192, wh[1], wl[1]);
    k_wsplit<<<256, 256, 0, stream>>>(d_in[6],  flags, 5,  192, 218, 192, wh[2], wl[2]);
    k_wsplit<<<256, 256, 0, stream>>>(d_in[8],  flags, 7,  218, 256, 224, wh[3], wl[3]);
    k_wsplit<<<128, 256, 0, stream>>>(d_in[12], flags, 11, 128, 128, 128, wh[5], wl[5]);
    k_wsplit<<<128, 256, 0, stream>>>(d_in[14], flags, 13, 128, 128, 128, wh[6], wl[6]);
    k_wsplit<<<128, 256, 0, stream>>>(d_in[16], flags, 15, 128, 128, 128, wh[7], wl[7]);
    k_biasall<<<8, 256, 0, stream>>>(tab, flags, mo, ball);

    k_repack<<<EB, 256, 0, stream>>>(ei, flags, src32, dst32);
    k_zero2<<<(NN + 255) / 256, 256, 0, stream>>>(deg, cursor, NN);
    k_count<<<EB, 256, 0, stream>>>(dst32, deg);
    k_scan1<<<NB512, 512, 0, stream>>>(deg, rowp, part);
    k_scan2<<<1, 128, 0, stream>>>(part, NB512);
    k_scan3<<<(NN + 255) / 256, 256, 0, stream>>>(rowp, part, deg, dinv);
    k_fill<<<EB, 256, 0, stream>>>(src32, dst32, rowp, cursor, colv);

    // initial: xs = x*dinv (bufA, stride 128) -> gather0 -> bufB (stride 128)
    k_xin<<<(NN * 16 + 255) / 256, 256, 0, stream>>>(d_in[0], flags, dinv, bufA);
    k_gather<<<GN, 256, 0, stream>>>(bufA, 128, bufB, 128, 16, rowp, colv, dinv);

    // L1 merged (e+n): bufB(128) -> bufA (stride 320 = [e192 | n128])
    k_mgemm<<<dim3(GX, 3), 256, 0, stream>>>(bufB, 128, wh[0], wl[0], 128, ball, dinv,
                                             bufA, 320, 320, 320, 0);
    k_gather<<<GN, 256, 0, stream>>>(bufA, 320, bufB, 320, 40, rowp, colv, dinv);

    // L2: e (K=192) + n (K=128), bufB(320) -> bufA(320)
    k_mgemm<<<dim3(GX, 2), 256, 0, stream>>>(bufB, 320, wh[1], wl[1], 192, ball + 320, dinv,
                                             bufA, 320, 192, 192, 0);
    k_mgemm<<<dim3(GX, 1), 256, 0, stream>>>(bufB + 192, 320, wh[5], wl[5], 128, ball + 992, dinv,
                                             bufA + 192, 320, 128, 128, 0);
    k_gather<<<GN, 256, 0, stream>>>(bufA, 320, bufB, 320, 40, rowp, colv, dinv);

    // L3: e (K=192 -> 224 wide) + n, bufB(320) -> bufA (stride 352 = [e224 | n128])
    k_mgemm<<<dim3(GX, 2), 256, 0, stream>>>(bufB, 320, wh[2], wl[2], 192, ball + 512, dinv,
                                             bufA, 352, 218, 224, 0);
    k_mgemm<<<dim3(GX, 1), 256, 0, stream>>>(bufB + 192, 320, wh[6], wl[6], 128, ball + 1120, dinv,
                                             bufA + 224, 352, 128, 128, 0);
    k_gather<<<GN, 256, 0, stream>>>(bufA, 352, bufB, 352, 44, rowp, colv, dinv);

    // L4: sigmoid outputs, fp32
    k_mgemm<<<dim3(GX, 2), 256, 0, stream>>>(bufB, 352, wh[3], wl[3], 224, ball + 736, dinv,
                                             out_e, 256, 256, 256, 1);
    k_mgemm<<<dim3(GX, 1), 256, 0, stream>>>(bufB + 224, 352, wh[7], wl[7], 128, ball + 1248, dinv,
                                             out_v, 128, 128, 128, 1);
}

// Round 2
// 511.447 us; speedup vs baseline: 1.3942x; 1.1751x over previous
//
#include <hip/hip_runtime.h>
#include <hip/hip_bf16.h>
#include <cstdint>
#include <cstddef>

typedef __hip_bfloat16 bf16;
typedef __attribute__((ext_vector_type(8))) short bf16x8;
typedef __attribute__((ext_vector_type(4))) float f32x4;

#define NN 50000
#define NE 400000

struct PTab {
    const void* p[17];
    int n[17];
};

__device__ __forceinline__ float bf2f(unsigned short u) {
    return __uint_as_float(((unsigned)u) << 16);
}
__device__ __forceinline__ unsigned short f2bf(float f) {
    __hip_bfloat16 h = __float2bfloat16(f);
    return *reinterpret_cast<unsigned short*>(&h);
}
__device__ __forceinline__ float fin(float v) {
    return (v == v && v > -1e30f && v < 1e30f) ? v : 0.0f;
}
__device__ __forceinline__ float rd(const void* p, int i, int f) {
    return f ? ((const float*)p)[i] : bf2f(((const unsigned short*)p)[i]);
}

// async global -> LDS, 16B per lane, dest = wave-uniform base + lane*16
__device__ __forceinline__ void gl16(const void* g, void* l) {
    __builtin_amdgcn_global_load_lds(
        (const __attribute__((address_space(1))) unsigned int*)g,
        (__attribute__((address_space(3))) unsigned int*)l, 16, 0, 0);
}

// ---- probe dtypes: flags[t]=1 fp32 / 0 bf16 (t=0..16); flags[17]=1 int32 ei ----
__global__ void k_probe(PTab tab, const int* __restrict__ ei, int* __restrict__ flags) {
    __shared__ int zc, bc, sAny;
    for (int t = 0; t < 17; ++t) {
        if (threadIdx.x == 0) { zc = 0; bc = 0; }
        __syncthreads();
        int words = tab.n[t] >> 1;
        if (words > 256) words = 256;
        if ((int)threadIdx.x < words) {
            unsigned w = ((const unsigned*)tab.p[t])[threadIdx.x];
            if (w == 0u) atomicAdd(&zc, 1);
            else {
                int e = (w >> 7) & 0xFF;
                if (e >= 100 && e <= 140) atomicAdd(&bc, 1);
            }
        }
        __syncthreads();
        if (threadIdx.x == 0) {
            int nz = words - zc;
            flags[t] = (nz == 0 || 2 * bc >= nz) ? 0 : 1;
        }
        __syncthreads();
    }
    if (threadIdx.x == 0) sAny = 0;
    __syncthreads();
    int any = 0;
    for (int i = threadIdx.x; i < 2048; i += 256) any |= ei[2 * i + 1];
    if (any) sAny = 1;
    __syncthreads();
    if (threadIdx.x == 0) flags[17] = sAny;
}

// ---- split W into transposed bf16 hi/lo: [rows][Kp], zero-padded ----
__global__ void k_wsplit(const void* __restrict__ W, const int* __restrict__ flags, int fidx,
                         int K, int M, int Kp,
                         unsigned short* __restrict__ wh, unsigned short* __restrict__ wl) {
    int n = blockIdx.x;
    int k = threadIdx.x;
    if (k >= Kp) return;
    float v = 0.0f;
    if (k < K && n < M) v = fin(rd(W, k * M + n, flags[fidx]));
    unsigned short hi = f2bf(v);
    unsigned short lo = f2bf(v - bf2f(hi));
    wh[(size_t)n * Kp + k] = hi;
    wl[(size_t)n * Kp + k] = lo;
}

struct MOff { int m[8]; int mp[8]; };

// ---- all 8 biases, zero-padded to mp[l] ----
__global__ void k_biasall(PTab tab, const int* __restrict__ flags, MOff mo,
                          float* __restrict__ dst) {
    int l = blockIdx.x;
    int fidx = 2 + 2 * l;
    int M = tab.n[fidx];
    int i = threadIdx.x;
    if (i < mo.mp[l])
        dst[mo.m[l] + i] = (i < M) ? fin(rd(tab.p[fidx], i, flags[fidx])) : 0.0f;
}

__global__ void k_repack(const int* __restrict__ ei, const int* __restrict__ flags,
                         int* __restrict__ src, int* __restrict__ dst) {
    int e = blockIdx.x * blockDim.x + threadIdx.x;
    if (e >= NE) return;
    int s, d;
    if (flags[17]) { s = ei[e]; d = ei[NE + e]; }
    else           { s = ei[2 * e]; d = ei[2 * (NE + e)]; }
    src[e] = min(max(s, 0), NN - 1);
    dst[e] = min(max(d, 0), NN - 1);
}

__global__ void k_zero2(int* __restrict__ a, int* __restrict__ b, int n) {
    int i = blockIdx.x * blockDim.x + threadIdx.x;
    if (i < n) { a[i] = 0; b[i] = 0; }
}

__global__ void k_count(const int* __restrict__ dst, int* __restrict__ deg) {
    int e = blockIdx.x * blockDim.x + threadIdx.x;
    if (e < NE) atomicAdd(&deg[dst[e]], 1);
}

__global__ void k_scan1(const int* __restrict__ deg, int* __restrict__ rowp,
                        int* __restrict__ part) {
    __shared__ int s[512];
    int tid = threadIdx.x, i = blockIdx.x * 512 + tid;
    int v = (i < NN) ? deg[i] : 0;
    s[tid] = v;
    __syncthreads();
    for (int off = 1; off < 512; off <<= 1) {
        int t = (tid >= off) ? s[tid - off] : 0;
        __syncthreads();
        s[tid] += t;
        __syncthreads();
    }
    if (i < NN) rowp[i] = s[tid] - v;
    if (tid == 511) part[blockIdx.x] = s[511];
}
__global__ void k_scan2(int* __restrict__ part, int nb) {
    __shared__ int s[128];
    int tid = threadIdx.x;
    int v = (tid < nb) ? part[tid] : 0;
    s[tid] = v;
    __syncthreads();
    for (int off = 1; off < 128; off <<= 1) {
        int t = (tid >= off) ? s[tid - off] : 0;
        __syncthreads();
        s[tid] += t;
        __syncthreads();
    }
    if (tid < nb) part[tid] = s[tid] - v;
}
__global__ void k_scan3(int* __restrict__ rowp, const int* __restrict__ part,
                        const int* __restrict__ deg, float* __restrict__ dinv) {
    int i = blockIdx.x * blockDim.x + threadIdx.x;
    if (i < NN) {
        rowp[i] += part[i >> 9];
        dinv[i] = rsqrtf((float)deg[i] + 1.0f);
    }
    if (i == 0) rowp[NN] = NE;
}

__global__ void k_fill(const int* __restrict__ src, const int* __restrict__ dst,
                       const int* __restrict__ rowp, int* __restrict__ cursor,
                       int* __restrict__ colv) {
    int e = blockIdx.x * blockDim.x + threadIdx.x;
    if (e >= NE) return;
    int d = dst[e];
    int p = atomicAdd(&cursor[d], 1);
    colv[rowp[d] + p] = src[e];
}

// ---- xs = bf16(x * dinv), stride 128 ----
__global__ void k_xin(const void* __restrict__ x, const int* __restrict__ flags,
                      const float* __restrict__ dinv, unsigned short* __restrict__ xs) {
    int t = blockIdx.x * blockDim.x + threadIdx.x;
    if (t >= NN * 16) return;
    int i = t >> 4, c = (t & 15) * 8;
    float d = dinv[i];
    int f = flags[0];
    const float* xf = (const float*)x + (size_t)i * 128 + c;
    const unsigned short* xb = (const unsigned short*)x + (size_t)i * 128 + c;
    unsigned short o[8];
    #pragma unroll
    for (int j = 0; j < 8; ++j)
        o[j] = f2bf(fin(f ? xf[j] : bf2f(xb[j])) * d);
    *(uint4*)(xs + (size_t)i * 128 + c) = *(uint4*)o;
}

// ---- CSR gather, fused-width: out[i]=dinv[i]*(in[i]+sum in[colv[j]]) ----
__launch_bounds__(256)
__global__ void k_gather(const unsigned short* __restrict__ in, int istride,
                         unsigned short* __restrict__ out, int ostride, int lanes,
                         const int* __restrict__ rowp, const int* __restrict__ colv,
                         const float* __restrict__ dinv) {
    const int node = blockIdx.x * 4 + (threadIdx.x >> 6);
    if (node >= NN) return;
    const int lane = threadIdx.x & 63;
    const int beg = rowp[node], end = rowp[node + 1];
    float a[8] = {0.f, 0.f, 0.f, 0.f, 0.f, 0.f, 0.f, 0.f};
    if (lanes <= 16) {
        const int slot = lane >> 4;
        const int l8 = lane & 15;
        const bool on = l8 < lanes;
        const size_t off = (size_t)l8 * 8;
        if (slot == 0 && on) {
            uint4 q = *(const uint4*)(in + (size_t)node * istride + off);
            unsigned v[4] = {q.x, q.y, q.z, q.w};
            #pragma unroll
            for (int t = 0; t < 4; ++t) {
                a[2 * t] += bf2f(v[t] & 0xFFFF); a[2 * t + 1] += bf2f(v[t] >> 16);
            }
        }
        for (int j = beg + slot; j < end; j += 4) {
            const int s = colv[j];
            if (on) {
                uint4 q = *(const uint4*)(in + (size_t)s * istride + off);
                unsigned v[4] = {q.x, q.y, q.z, q.w};
                #pragma unroll
                for (int t = 0; t < 4; ++t) {
                    a[2 * t] += bf2f(v[t] & 0xFFFF); a[2 * t + 1] += bf2f(v[t] >> 16);
                }
            }
        }
        #pragma unroll
        for (int t = 0; t < 8; ++t) {
            a[t] += __shfl_xor(a[t], 16);
            a[t] += __shfl_xor(a[t], 32);
        }
        if (lane < lanes) {
            float d = dinv[node];
            unsigned short o[8];
            #pragma unroll
            for (int t = 0; t < 8; ++t) o[t] = f2bf(a[t] * d);
            *(uint4*)(out + (size_t)node * ostride + (size_t)lane * 8) = *(uint4*)o;
        }
    } else {
        const bool on = lane < lanes;
        const size_t off = (size_t)lane * 8;
        if (on) {
            uint4 q = *(const uint4*)(in + (size_t)node * istride + off);
            unsigned v[4] = {q.x, q.y, q.z, q.w};
            #pragma unroll
            for (int t = 0; t < 4; ++t) {
                a[2 * t] += bf2f(v[t] & 0xFFFF); a[2 * t + 1] += bf2f(v[t] >> 16);
            }
        }
        int j = beg;
        for (; j + 3 < end; j += 4) {
            int s0 = colv[j], s1 = colv[j + 1], s2 = colv[j + 2], s3 = colv[j + 3];
            if (on) {
                uint4 q0 = *(const uint4*)(in + (size_t)s0 * istride + off);
                uint4 q1 = *(const uint4*)(in + (size_t)s1 * istride + off);
                uint4 q2 = *(const uint4*)(in + (size_t)s2 * istride + off);
                uint4 q3 = *(const uint4*)(in + (size_t)s3 * istride + off);
                unsigned v0[4] = {q0.x, q0.y, q0.z, q0.w};
                unsigned v1[4] = {q1.x, q1.y, q1.z, q1.w};
                unsigned v2[4] = {q2.x, q2.y, q2.z, q2.w};
                unsigned v3[4] = {q3.x, q3.y, q3.z, q3.w};
                #pragma unroll
                for (int t = 0; t < 4; ++t) {
                    a[2 * t]     += bf2f(v0[t] & 0xFFFF) + bf2f(v1[t] & 0xFFFF)
                                  + bf2f(v2[t] & 0xFFFF) + bf2f(v3[t] & 0xFFFF);
                    a[2 * t + 1] += bf2f(v0[t] >> 16) + bf2f(v1[t] >> 16)
                                  + bf2f(v2[t] >> 16) + bf2f(v3[t] >> 16);
                }
            }
        }
        for (; j < end; ++j) {
            int s = colv[j];
            if (on) {
                uint4 q = *(const uint4*)(in + (size_t)s * istride + off);
                unsigned v[4] = {q.x, q.y, q.z, q.w};
                #pragma unroll
                for (int t = 0; t < 4; ++t) {
                    a[2 * t] += bf2f(v[t] & 0xFFFF); a[2 * t + 1] += bf2f(v[t] >> 16);
                }
            }
        }
        if (on) {
            float d = dinv[node];
            unsigned short o[8];
            #pragma unroll
            for (int t = 0; t < 8; ++t) o[t] = f2bf(a[t] * d);
            *(uint4*)(out + (size_t)node * ostride + off) = *(uint4*)o;
        }
    }
}

// ---- merged GEMM side params ----
struct GSide {
    const unsigned short* A;
    const unsigned short* Wh;
    const unsigned short* Wl;
    const float* bias;
    void* out;
    int Kp, ostride, M, OutW, act;
};

// ---- MFMA GEMM: gl16 staging, linear+XOR-swizzled LDS, 1-ahead double buffer,
//      merged dual-side launch (y<ySplit -> s0, else s1), LDS-bounced epilogue ----
__launch_bounds__(256, 3)
__global__ void k_mgemm(GSide s0, GSide s1, int ySplit, int astride,
                        const float* __restrict__ dinv) {
    __shared__ __align__(16) unsigned char ldsraw[49152];
    auto sA  = reinterpret_cast<unsigned short (*)[128][32]>(ldsraw);
    auto sBh = reinterpret_cast<unsigned short (*)[128][32]>(ldsraw + 16384);
    auto sBl = reinterpret_cast<unsigned short (*)[128][32]>(ldsraw + 32768);

    const int tid = threadIdx.x;
    const int wave = tid >> 6, lane = tid & 63;
    const int wr = wave >> 1, wc = wave & 1;
    const int quad = lane >> 4, m16 = lane & 15;

    GSide S; int ycol;
    if ((int)blockIdx.y < ySplit) { S = s0; ycol = blockIdx.y; }
    else                          { S = s1; ycol = blockIdx.y - ySplit; }
    const int row0 = blockIdx.x * 128, col0 = ycol * 128;
    const int Kp = S.Kp;

    // staging: wave stages rows [wave*32, wave*32+32); lane -> (row, 16B unit)
    const int lr = lane >> 2;
    const int swz = ((lane >> 2) ^ (lane >> 4)) & 3;
    const int su = ((lane & 3) ^ swz) * 8;

    int ar1 = row0 + wave * 32 + lr;      if (ar1 >= NN) ar1 = NN - 1;
    int ar2 = row0 + wave * 32 + 16 + lr; if (ar2 >= NN) ar2 = NN - 1;
    const unsigned short* gA1 = S.A + (size_t)ar1 * astride + su;
    const unsigned short* gA2 = S.A + (size_t)ar2 * astride + su;
    const int br = col0 + wave * 32 + lr;
    const unsigned short* gBh1 = S.Wh + (size_t)br * Kp + su;
    const unsigned short* gBl1 = S.Wl + (size_t)br * Kp + su;

    f32x4 zz = {0.f, 0.f, 0.f, 0.f};
    f32x4 acc[4][4];
    #pragma unroll
    for (int i = 0; i < 4; ++i)
        #pragma unroll
        for (int j = 0; j < 4; ++j) acc[i][j] = zz;

    const int rs = (quad ^ ((m16 & 3) ^ ((m16 >> 2) & 3))) * 8;
    const int nk = Kp >> 5;

    auto stage = [&](int b, int k0) {
        gl16(gA1 + k0,            &sA[b][wave * 32][0]);
        gl16(gA2 + k0,            &sA[b][wave * 32 + 16][0]);
        gl16(gBh1 + k0,           &sBh[b][wave * 32][0]);
        gl16(gBh1 + 16 * Kp + k0, &sBh[b][wave * 32 + 16][0]);
        gl16(gBl1 + k0,           &sBl[b][wave * 32][0]);
        gl16(gBl1 + 16 * Kp + k0, &sBl[b][wave * 32 + 16][0]);
    };

    stage(0, 0);
    __syncthreads();
    int cur = 0;
    for (int ks = 0; ks < nk; ++ks) {
        if (ks + 1 < nk) stage(cur ^ 1, (ks + 1) * 32);
        bf16x8 fa[4], fh[4], fl[4];
        #pragma unroll
        for (int i = 0; i < 4; ++i) {
            fa[i] = *(const bf16x8*)&sA[cur][wr * 64 + i * 16 + m16][rs];
            fh[i] = *(const bf16x8*)&sBh[cur][wc * 64 + i * 16 + m16][rs];
            fl[i] = *(const bf16x8*)&sBl[cur][wc * 64 + i * 16 + m16][rs];
        }
        #pragma unroll
        for (int i = 0; i < 4; ++i)
            #pragma unroll
            for (int j = 0; j < 4; ++j) {
                acc[i][j] = __builtin_amdgcn_mfma_f32_16x16x32_bf16(fa[i], fh[j], acc[i][j], 0, 0, 0);
                acc[i][j] = __builtin_amdgcn_mfma_f32_16x16x32_bf16(fa[i], fl[j], acc[i][j], 0, 0, 0);
            }
        __syncthreads();
        cur ^= 1;
    }

    // ---- epilogue: stage per-wave 16x64 f32 tile in LDS, store coalesced ----
    // per-wave area: 16 rows x 68 f32 (padded) = 4352B, reuses dead sA region
    float* eps = (float*)(ldsraw + (size_t)wave * 4352);
    #pragma unroll
    for (int i = 0; i < 4; ++i) {
        #pragma unroll
        for (int j = 0; j < 4; ++j) {
            int col = col0 + wc * 64 + j * 16 + m16;
            float bcol = (col < S.M) ? S.bias[col] : 0.0f;
            #pragma unroll
            for (int r = 0; r < 4; ++r) {
                float v = acc[i][j][r] + bcol;
                if (S.act) v = (col < S.M) ? 1.0f / (1.0f + expf(-v)) : 0.0f;
                else       v = (col < S.M) ? fmaxf(v, 0.0f) : 0.0f;
                eps[(quad * 4 + r) * 68 + j * 16 + m16] = v;
            }
        }
        asm volatile("s_waitcnt lgkmcnt(0)" ::: "memory");
        __builtin_amdgcn_sched_barrier(0);
        #pragma unroll
        for (int it = 0; it < 4; ++it) {
            int lr2 = it * 4 + (lane >> 4);
            int c4 = (lane & 15) * 4;
            float4 w = *(float4*)&eps[lr2 * 68 + c4];
            int grow = row0 + wr * 64 + i * 16 + lr2;
            int gcol = col0 + wc * 64 + c4;
            if (grow < NN && gcol < S.OutW) {
                if (S.act) {
                    *(float4*)((float*)S.out + (size_t)grow * S.ostride + gcol) = w;
                } else {
                    float d = dinv[grow];
                    unsigned o0 = f2bf(w.x * d) | ((unsigned)f2bf(w.y * d) << 16);
                    unsigned o1 = f2bf(w.z * d) | ((unsigned)f2bf(w.w * d) << 16);
                    uint2 u; u.x = o0; u.y = o1;
                    *(uint2*)((unsigned short*)S.out + (size_t)grow * S.ostride + gcol) = u;
                }
            }
        }
        asm volatile("s_waitcnt lgkmcnt(0)" ::: "memory");
        __builtin_amdgcn_sched_barrier(0);
    }
}

__global__ void k_sentinel(float* __restrict__ out, int n) {
    int i = blockIdx.x * blockDim.x + threadIdx.x;
    if (i < n) out[i] = 4.0f;
}

extern "C" void kernel_launch(void* const* d_in, const int* in_sizes, int n_in,
                              void* d_out, int out_size, void* d_ws, size_t ws_size,
                              hipStream_t stream) {
    const int* ei = (const int*)d_in[1];
    float* out_e = (float*)d_out;
    float* out_v = out_e + (size_t)NN * 256;

    const int wsz[16] = {128 * 166, 166, 166 * 192, 192, 192 * 218, 218, 218 * 256, 256,
                         128 * 128, 128, 128 * 128, 128, 128 * 128, 128, 128 * 128, 128};
    PTab tab;
    tab.p[0] = d_in[0]; tab.n[0] = NN * 128;
    for (int t = 0; t < 16; ++t) { tab.p[t + 1] = d_in[2 + t]; tab.n[t + 1] = wsz[t]; }

    // weight storage: l=0 is merged [W1e(pad192) | W1n] 384x128; l=4 unused
    const int KpW[8] = {128, 192, 192, 224, 0, 128, 128, 128};
    const int MpW[8] = {384, 256, 256, 256, 0, 128, 128, 128};

    char* wsb = (char*)d_ws;
    size_t o = 0;
    auto align = [](size_t v) { return (v + 255) & ~(size_t)255; };
    int*   flags  = (int*)(wsb + o);  o = align(o + 128);
    int*   colv   = (int*)(wsb + o);  o = align(o + (size_t)NE * 4);
    int*   deg    = (int*)(wsb + o);  o = align(o + (size_t)NN * 4);
    int*   cursor = (int*)(wsb + o);  o = align(o + (size_t)NN * 4);
    int*   rowp   = (int*)(wsb + o);  o = align(o + (size_t)(NN + 1) * 4);
    int*   part   = (int*)(wsb + o);  o = align(o + 512);
    float* dinv   = (float*)(wsb + o); o = align(o + (size_t)NN * 4);
    unsigned short* wh[8]; unsigned short* wl[8];
    for (int l = 0; l < 8; ++l) {
        size_t wel = (size_t)MpW[l] * KpW[l];
        wh[l] = (unsigned short*)(wsb + o); o = align(o + wel * 2);
        wl[l] = (unsigned short*)(wsb + o); o = align(o + wel * 2);
    }
    float* ball = (float*)(wsb + o); o = align(o + 1376 * 4);
    unsigned short* bufA = (unsigned short*)(wsb + o); o = align(o + (size_t)NN * 352 * 2);
    unsigned short* bufB = (unsigned short*)(wsb + o); o = align(o + (size_t)NN * 352 * 2);
    int* src32 = (int*)bufB;
    int* dst32 = src32 + NE;
    if (o > ws_size) {
        k_sentinel<<<(out_size + 255) / 256, 256, 0, stream>>>(out_e, out_size);
        return;
    }

    // bias packing: merged L1 bias = [b1e pad192 | b1n] at [0,320)
    MOff mo;
    const int moff[8] = {0, 320, 512, 736, 192, 992, 1120, 1248};
    const int mpad[8] = {192, 192, 224, 256, 128, 128, 128, 128};
    for (int l = 0; l < 8; ++l) { mo.m[l] = moff[l]; mo.mp[l] = mpad[l]; }

    const int EB = (NE + 255) / 256;
    const int NB512 = (NN + 511) / 512;
    const int GX = (NN + 127) / 128;
    const int GN = (NN + 3) / 4;

    k_probe<<<1, 256, 0, stream>>>(tab, ei, flags);
    k_wsplit<<<192, 256, 0, stream>>>(d_in[2],  flags, 1,  128, 166, 128, wh[0], wl[0]);
    k_wsplit<<<192, 256, 0, stream>>>(d_in[10], flags, 9,  128, 128, 128,
                                      wh[0] + 192 * 128, wl[0] + 192 * 128);
    k_wsplit<<<256, 256, 0, stream>>>(d_in[4],  flags, 3,  166, 192, 192, wh[1], wl[1]);
    k_wsplit<<<256, 256, 0, stream>>>(d_in[6],  flags, 5,  192, 218, 192, wh[2], wl[2]);
    k_wsplit<<<256, 256, 0, stream>>>(d_in[8],  flags, 7,  218, 256, 224, wh[3], wl[3]);
    k_wsplit<<<128, 256, 0, stream>>>(d_in[12], flags, 11, 128, 128, 128, wh[5], wl[5]);
    k_wsplit<<<128, 256, 0, stream>>>(d_in[14], flags, 13, 128, 128, 128, wh[6], wl[6]);
    k_wsplit<<<128, 256, 0, stream>>>(d_in[16], flags, 15, 128, 128, 128, wh[7], wl[7]);
    k_biasall<<<8, 256, 0, stream>>>(tab, flags, mo, ball);

    k_repack<<<EB, 256, 0, stream>>>(ei, flags, src32, dst32);
    k_zero2<<<(NN + 255) / 256, 256, 0, stream>>>(deg, cursor, NN);
    k_count<<<EB, 256, 0, stream>>>(dst32, deg);
    k_scan1<<<NB512, 512, 0, stream>>>(deg, rowp, part);
    k_scan2<<<1, 128, 0, stream>>>(part, NB512);
    k_scan3<<<(NN + 255) / 256, 256, 0, stream>>>(rowp, part, deg, dinv);
    k_fill<<<EB, 256, 0, stream>>>(src32, dst32, rowp, cursor, colv);

    // initial: xs = x*dinv (bufA, stride 128) -> gather0 -> bufB (stride 128)
    k_xin<<<(NN * 16 + 255) / 256, 256, 0, stream>>>(d_in[0], flags, dinv, bufA);
    k_gather<<<GN, 256, 0, stream>>>(bufA, 128, bufB, 128, 16, rowp, colv, dinv);

    // L1 merged (e+n): bufB(128) -> bufA (stride 320 = [e192 | n128])
    {
        GSide s0 = {bufB, wh[0], wl[0], ball, bufA, 128, 320, 320, 320, 0};
        k_mgemm<<<dim3(GX, 3), 256, 0, stream>>>(s0, s0, 3, 128, dinv);
    }
    k_gather<<<GN, 256, 0, stream>>>(bufA, 320, bufB, 320, 40, rowp, colv, dinv);

    // L2: e (K=192, 2 col-blocks) + n (K=128, 1 col-block), one launch
    {
        GSide s0 = {bufB, wh[1], wl[1], ball + 320, bufA, 192, 320, 192, 192, 0};
        GSide s1 = {bufB + 192, wh[5], wl[5], ball + 992, bufA + 192, 128, 320, 128, 128, 0};
        k_mgemm<<<dim3(GX, 3), 256, 0, stream>>>(s0, s1, 2, 320, dinv);
    }
    k_gather<<<GN, 256, 0, stream>>>(bufA, 320, bufB, 320, 40, rowp, colv, dinv);

    // L3: e (K=192 -> 224 wide) + n, one launch; out stride 352 = [e224 | n128]
    {
        GSide s0 = {bufB, wh[2], wl[2], ball + 512, bufA, 192, 352, 218, 224, 0};
        GSide s1 = {bufB + 192, wh[6], wl[6], ball + 1120, bufA + 224, 128, 352, 128, 128, 0};
        k_mgemm<<<dim3(GX, 3), 256, 0, stream>>>(s0, s1, 2, 320, dinv);
    }
    k_gather<<<GN, 256, 0, stream>>>(bufA, 352, bufB, 352, 44, rowp, colv, dinv);

    // L4: sigmoid outputs, fp32, one launch
    {
        GSide s0 = {bufB, wh[3], wl[3], ball + 736, out_e, 224, 256, 256, 256, 1};
        GSide s1 = {bufB + 224, wh[7], wl[7], ball + 1248, out_v, 128, 128, 128, 128, 1};
        k_mgemm<<<dim3(GX, 3), 256, 0, stream>>>(s0, s1, 2, 352, dinv);
    }
}